// Round 4
// baseline (190.336 us; speedup 1.0000x reference)
//
#include <hip/hip_runtime.h>
#include <hip/hip_bf16.h>

// Problem sizes (fixed by the reference)
#define B_  32
#define L_  512
#define D_  512
#define H_  8
#define HD_ 64

typedef __attribute__((ext_vector_type(8))) short bf16x8;   // 8 bf16 (4 VGPRs)
typedef __attribute__((ext_vector_type(4))) short bf16x4;
typedef __attribute__((ext_vector_type(4))) float f32x4;

__device__ __forceinline__ short f2bf(float f) {
  union { float f; unsigned u; } x; x.f = f;
  unsigned r = x.u + 0x7FFFu + ((x.u >> 16) & 1u);   // RNE truncation
  return (short)(r >> 16);
}

// async global->LDS, 16B per lane; dest base must be wave-uniform (HW adds lane*16)
__device__ __forceinline__ void gll16(const void* g, void* l) {
  __builtin_amdgcn_global_load_lds(
      (const __attribute__((address_space(1))) unsigned int*)g,
      (__attribute__((address_space(3))) unsigned int*)l, 16, 0, 0);
}

// 8x f32 -> bf16x8 via v_cvt_pk_bf16_f32 (compiler lowers __float22bfloat162_rn)
__device__ __forceinline__ bf16x8 cvt8(f32x4 a, f32x4 b) {
  union { __hip_bfloat162 h[4]; bf16x8 v; } u;
  u.h[0] = __float22bfloat162_rn(float2{a[0], a[1]});
  u.h[1] = __float22bfloat162_rn(float2{a[2], a[3]});
  u.h[2] = __float22bfloat162_rn(float2{b[0], b[1]});
  u.h[3] = __float22bfloat162_rn(float2{b[2], b[3]});
  return u.v;
}

// same-wave LDS write->read ordering fence (rule 18: sched_barrier after asm waitcnt)
#define DS_FENCE() do { asm volatile("s_waitcnt lgkmcnt(0)" ::: "memory"); \
                        __builtin_amdgcn_sched_barrier(0); } while (0)

// --------------------------------------------------------------------------
// Weight transpose + convert: wt[w][n][k] = bf16(W_w[k][n]), w = 0..3
// --------------------------------------------------------------------------
__global__ __launch_bounds__(256) void wt_kernel(
    const float* __restrict__ WQ, const float* __restrict__ WK,
    const float* __restrict__ WV, const float* __restrict__ WO,
    short* __restrict__ wt) {
  __shared__ float tile[32][33];
  int wz = blockIdx.z;
  const float* W = (wz == 0) ? WQ : (wz == 1) ? WK : (wz == 2) ? WV : WO;
  int k0 = blockIdx.y * 32, n0 = blockIdx.x * 32;
  int tr = threadIdx.x >> 5, tc = threadIdx.x & 31;
#pragma unroll
  for (int i = 0; i < 4; ++i)
    tile[tr + i * 8][tc] = W[(size_t)(k0 + tr + i * 8) * D_ + n0 + tc];
  __syncthreads();
#pragma unroll
  for (int i = 0; i < 4; ++i)
    wt[((size_t)wz * D_ + n0 + tr + i * 8) * D_ + k0 + tc] =
        f2bf(tile[tc][tr + i * 8]);
}

// --------------------------------------------------------------------------
// QKV projection GEMM, prefetch-pipelined:
//  - A (f32) loaded per-wave global->reg one kk-phase ahead, cvt_pk to bf16
//  - B (bf16 WT) double-buffered LDS via global_load_lds, issued one full
//    K-step ahead => __syncthreads' vmcnt(0) drain waits only on OLD loads.
// LDS 32KB, ~164 VGPR target -> 3 blocks/CU (12 waves).
// Output layouts: Q,K -> [b,h,l,hd] bf16; V -> [b,h,hd,l] bf16.
// --------------------------------------------------------------------------
__global__ __launch_bounds__(256, 3) void gemm_qkv(
    const float* __restrict__ Xq, const float* __restrict__ Xk,
    const float* __restrict__ Xv, const short* __restrict__ wt,
    const float* __restrict__ bQ, const float* __restrict__ bK,
    const float* __restrict__ bV,
    short* __restrict__ q_ws, short* __restrict__ k_ws,
    short* __restrict__ vt_ws) {
  __shared__ __align__(16) char Bl[2][16384];   // bf16 B tile [128][64], dbuf

  int mode = blockIdx.z;
  const float* A = (mode == 0) ? Xq : (mode == 1) ? Xk : Xv;
  const short* WT = wt + (size_t)mode * D_ * D_;
  const float* bias = (mode == 0) ? bQ : (mode == 1) ? bK : bV;

  // XCD swizzle: the 4 n-tiles sharing the same A-rows land on one XCD.
  int wgid = blockIdx.x + 4 * blockIdx.y;   // 0..511 (512 % 8 == 0: bijective)
  int rr_ = wgid >> 3;
  int m0 = ((wgid & 7) * 16 + (rr_ >> 2)) * 128;
  int n0 = (rr_ & 3) * 128;

  int tid = threadIdx.x, lane = tid & 63, w = tid >> 6;
  int wr = w >> 1, wc = w & 1, g = lane >> 4, lr = lane & 15;
  int rowin = lane >> 3, sch8 = ((lane & 7) ^ rowin) * 8;  // B pre-swizzle

  // per-lane A fragment base: row = m0 + wr*64 + i*16 + lr, k = it*64+kk*32+g*8
  const float* Ab = A + (size_t)(m0 + wr * 64 + lr) * D_ + g * 8;

  f32x4 acc[4][4] = {};
  bf16x8 acur[4][2];

  // ---- prologue: issue B_0, load+cvt A_0 ----
#pragma unroll
  for (int j = 0; j < 4; ++j) {
    int e = w * 4 + j, row = e * 8 + rowin;
    gll16(WT + (size_t)(n0 + row) * D_ + sch8, &Bl[0][e * 1024]);
  }
#pragma unroll
  for (int i = 0; i < 4; ++i)
#pragma unroll
    for (int kk = 0; kk < 2; ++kk) {
      const float* p = Ab + (size_t)i * (16 * D_) + kk * 32;
      acur[i][kk] = cvt8(*(const f32x4*)p, *(const f32x4*)(p + 4));
    }

#pragma unroll
  for (int it = 0; it < 8; ++it) {
    __syncthreads();   // publishes B_it (its gll16s are one full step old)
    if (it < 7) {      // issue B_{it+1} now -> free drain at next barrier
#pragma unroll
      for (int j = 0; j < 4; ++j) {
        int e = w * 4 + j, row = e * 8 + rowin;
        gll16(WT + (size_t)(n0 + row) * D_ + (it + 1) * 64 + sch8,
              &Bl[(it + 1) & 1][e * 1024]);
      }
    }
    f32x4 nx0[4], nx1[4], ny0[4], ny1[4];
    if (it < 7) {      // prefetch next-A kk=0 (f32, consumed after kk0 compute)
#pragma unroll
      for (int i = 0; i < 4; ++i) {
        const float* p = Ab + (size_t)i * (16 * D_) + (it + 1) * 64;
        nx0[i] = *(const f32x4*)p;
        nx1[i] = *(const f32x4*)(p + 4);
      }
    }
    // ---- compute kk = 0 ----
    bf16x8 bf_[4];
#pragma unroll
    for (int i = 0; i < 4; ++i) {
      int row = wc * 64 + i * 16 + lr;          // row & 7 == lr & 7
      bf_[i] = *(const bf16x8*)(&Bl[it & 1][row * 128 + ((g ^ (lr & 7)) << 4)]);
    }
#pragma unroll
    for (int mi = 0; mi < 4; ++mi)
#pragma unroll
      for (int nj = 0; nj < 4; ++nj)
        acc[mi][nj] = __builtin_amdgcn_mfma_f32_16x16x32_bf16(
            acur[mi][0], bf_[nj], acc[mi][nj], 0, 0, 0);
    if (it < 7) {
#pragma unroll
      for (int i = 0; i < 4; ++i) acur[i][0] = cvt8(nx0[i], nx1[i]);
#pragma unroll
      for (int i = 0; i < 4; ++i) {  // prefetch next-A kk=1
        const float* p = Ab + (size_t)i * (16 * D_) + (it + 1) * 64 + 32;
        ny0[i] = *(const f32x4*)p;
        ny1[i] = *(const f32x4*)(p + 4);
      }
    }
    // ---- compute kk = 1 ----
#pragma unroll
    for (int i = 0; i < 4; ++i) {
      int row = wc * 64 + i * 16 + lr;
      bf_[i] = *(const bf16x8*)(&Bl[it & 1][row * 128 +
                                           (((4 + g) ^ (lr & 7)) << 4)]);
    }
#pragma unroll
    for (int mi = 0; mi < 4; ++mi)
#pragma unroll
      for (int nj = 0; nj < 4; ++nj)
        acc[mi][nj] = __builtin_amdgcn_mfma_f32_16x16x32_bf16(
            acur[mi][1], bf_[nj], acc[mi][nj], 0, 0, 0);
    if (it < 7) {
#pragma unroll
      for (int i = 0; i < 4; ++i) acur[i][1] = cvt8(ny0[i], ny1[i]);
    }
  }

  // Epilogue. C layout: row = g*4 + rr, col = lr (m89-verified).
#pragma unroll
  for (int mi = 0; mi < 4; ++mi) {
#pragma unroll
    for (int nj = 0; nj < 4; ++nj) {
      int n = n0 + wc * 64 + nj * 16 + lr;
      float bb = bias[n];
      int h = n >> 6, hd = n & 63;
#pragma unroll
      for (int rr = 0; rr < 4; ++rr) {
        int m = m0 + wr * 64 + mi * 16 + g * 4 + rr;
        int b = m >> 9, l = m & 511;
        short v = f2bf(acc[mi][nj][rr] + bb);
        if (mode == 0)
          q_ws[(((size_t)b * H_ + h) * L_ + l) * HD_ + hd] = v;
        else if (mode == 1)
          k_ws[(((size_t)b * H_ + h) * L_ + l) * HD_ + hd] = v;
        else
          vt_ws[(((size_t)b * H_ + h) * HD_ + hd) * L_ + l] = v;
      }
    }
  }
}

// --------------------------------------------------------------------------
// Attention, flash-style: block = 64 q-rows of one (b,h); 4 waves x 16 rows.
// 8 chunks of 64 keys; K/V chunk staged in LDS via global_load_lds (shared by
// all 4 waves, double-buffered, XOR-swizzled via pre-swizzled source), online
// softmax (small register state -> 4 waves/SIMD occupancy target).
// LDS: K 2x8KB | V^T 2x8KB | P 4x2KB = 40KB -> 4 blocks/CU.
// --------------------------------------------------------------------------
__global__ __launch_bounds__(256, 4) void attn_kernel(
    const short* __restrict__ q_ws, const short* __restrict__ k_ws,
    const short* __restrict__ vt_ws, const float* __restrict__ mask,
    short* __restrict__ ctx_ws) {
  __shared__ __align__(16) char lds[40960];
  int wg = blockIdx.x;                            // 2048 blocks, 2048%8==0
  int bh   = (wg & 7) * 32 + (wg >> 6);           // XCD-bijective: 32 heads/XCD
  int qblk = (wg >> 3) & 7;
  int b = bh >> 3, h = bh & 7;
  int tid = threadIdx.x, lane = tid & 63, w = tid >> 6;
  int g = lane >> 4, lr = lane & 15;
  char* Pl = lds + 32768 + w * 2048;              // per-wave P tile 16x64 bf16
  int qbase = qblk * 64 + w * 16;

  const short* Qh  = q_ws  + (size_t)bh * (L_ * HD_);
  const short* Kh  = k_ws  + (size_t)bh * (L_ * HD_);
  const short* VTh = vt_ws + (size_t)bh * (HD_ * L_);
  const float* mrow = mask + (size_t)b * L_;

  // Q fragments (A-operand): row = lr, k = g*8+j, two hd-halves
  bf16x8 aq0 = *(const bf16x8*)(Qh + (size_t)(qbase + lr) * HD_ + g * 8);
  bf16x8 aq1 = *(const bf16x8*)(Qh + (size_t)(qbase + lr) * HD_ + 32 + g * 8);

  // staging lane constants: 1KB issue = 8 rows x 128B; slot s holds chunk s^row
  int rowin = lane >> 3;
  int sch8 = ((lane & 7) ^ rowin) * 8;   // pre-swizzled source offset (shorts)

  // prologue: stage chunk 0 into buffer 0
#pragma unroll
  for (int j = 0; j < 2; ++j) {
    int e = w * 2 + j, row = e * 8 + rowin;
    gll16(Kh + (size_t)row * HD_ + sch8, lds + e * 1024);
    gll16(VTh + (size_t)row * L_ + sch8, lds + 16384 + e * 1024);
  }
  __syncthreads();

  f32x4 c[4] = {};
  float m[4] = {-1e30f, -1e30f, -1e30f, -1e30f};
  float sum[4] = {0.f, 0.f, 0.f, 0.f};

  for (int ch = 0; ch < 8; ++ch) {
    const char* Kb = lds + (ch & 1) * 8192;
    const char* Vb = lds + 16384 + (ch & 1) * 8192;
    if (ch < 7) {  // issue next chunk's stage first: overlaps this compute
      char* Kn = lds + ((ch + 1) & 1) * 8192;
      char* Vn = lds + 16384 + ((ch + 1) & 1) * 8192;
#pragma unroll
      for (int j = 0; j < 2; ++j) {
        int e = w * 2 + j, row = e * 8 + rowin;
        gll16(Kh + ((size_t)(ch + 1) * 64 + row) * HD_ + sch8, Kn + e * 1024);
        gll16(VTh + (size_t)row * L_ + (ch + 1) * 64 + sch8, Vn + e * 1024);
      }
    }
    float mb[4];
#pragma unroll
    for (int kt = 0; kt < 4; ++kt)
      mb[kt] = (1.0f - mrow[ch * 64 + kt * 16 + lr]) * -1e9f;

    // ---- QK^T for this chunk: s[4] = 16 q-rows x 64 keys ----
    f32x4 s[4];
#pragma unroll
    for (int kt = 0; kt < 4; ++kt) {
      int row = kt * 16 + lr;                      // row & 7 == lr & 7
      bf16x8 bk0 = *(const bf16x8*)(Kb + row * 128 + ((g ^ (lr & 7)) << 4));
      bf16x8 bk1 = *(const bf16x8*)(Kb + row * 128 + (((4 + g) ^ (lr & 7)) << 4));
      f32x4 a = {0.f, 0.f, 0.f, 0.f};
      a = __builtin_amdgcn_mfma_f32_16x16x32_bf16(aq0, bk0, a, 0, 0, 0);
      a = __builtin_amdgcn_mfma_f32_16x16x32_bf16(aq1, bk1, a, 0, 0, 0);
#pragma unroll
      for (int rr = 0; rr < 4; ++rr) a[rr] = a[rr] * 0.125f + mb[kt];
      s[kt] = a;
    }

    // ---- online softmax update (rows g*4+rr; cols lr+16*kt) ----
    float pmax[4], scl[4];
#pragma unroll
    for (int rr = 0; rr < 4; ++rr)
      pmax[rr] = fmaxf(fmaxf(s[0][rr], s[1][rr]), fmaxf(s[2][rr], s[3][rr]));
#pragma unroll
    for (int off = 1; off < 16; off <<= 1)
#pragma unroll
      for (int rr = 0; rr < 4; ++rr)
        pmax[rr] = fmaxf(pmax[rr], __shfl_xor(pmax[rr], off, 64));
#pragma unroll
    for (int rr = 0; rr < 4; ++rr) {
      float mn = fmaxf(m[rr], pmax[rr]);
      scl[rr] = __expf(m[rr] - mn);
      m[rr] = mn;
      sum[rr] *= scl[rr];
    }
#pragma unroll
    for (int nt = 0; nt < 4; ++nt)
#pragma unroll
      for (int rr = 0; rr < 4; ++rr) c[nt][rr] *= scl[rr];

    // P -> wave-private LDS tile (XOR-swizzled rows of 128B)
#pragma unroll
    for (int kt = 0; kt < 4; ++kt) {
      int col2 = (kt * 16 + lr) * 2;
#pragma unroll
      for (int rr = 0; rr < 4; ++rr) {
        float p = __expf(s[kt][rr] - m[rr]);
        sum[rr] += p;
        int row = g * 4 + rr;
        *(short*)(Pl + row * 128 + (col2 ^ ((row & 7) << 4))) = f2bf(p);
      }
    }
    DS_FENCE();   // own-wave P writes visible before transposed reads

    // ---- PV accumulate: c += P(16x64) @ V(64x64) ----
#pragma unroll
    for (int kk = 0; kk < 2; ++kk) {
      bf16x8 ap = *(const bf16x8*)(Pl + lr * 128 +
                                   (((kk * 4 + g) ^ (lr & 7)) << 4));
#pragma unroll
      for (int nt = 0; nt < 4; ++nt) {
        int row = nt * 16 + lr;
        bf16x8 bv = *(const bf16x8*)(Vb + row * 128 +
                                     (((kk * 4 + g) ^ (lr & 7)) << 4));
        c[nt] = __builtin_amdgcn_mfma_f32_16x16x32_bf16(ap, bv, c[nt], 0, 0, 0);
      }
    }
    DS_FENCE();   // P reads drained before next chunk's P writes (WAR)
    if (ch < 7) __syncthreads();   // next staged buffer ready for all waves
  }

  float inv[4];
#pragma unroll
  for (int off = 1; off < 16; off <<= 1)
#pragma unroll
    for (int rr = 0; rr < 4; ++rr) sum[rr] += __shfl_xor(sum[rr], off, 64);
#pragma unroll
  for (int rr = 0; rr < 4; ++rr) inv[rr] = 1.0f / sum[rr];

  // epilogue: ctx_ws[b][l][h][hd] (row-major [16384][512] for the out-GEMM)
#pragma unroll
  for (int nt = 0; nt < 4; ++nt) {
    int hd = nt * 16 + lr;
#pragma unroll
    for (int rr = 0; rr < 4; ++rr) {
      int qrow = qbase + g * 4 + rr;
      ctx_ws[(((size_t)b * L_ + qrow) * H_ + h) * HD_ + hd] =
          f2bf(c[nt][rr] * inv[rr]);
    }
  }
}

// --------------------------------------------------------------------------
// Output GEMM (bf16 x bf16 -> f32), same prefetch pipeline as gemm_qkv:
// A (ctx, bf16) per-wave global->reg one step ahead; B dbuf LDS via gll16.
// --------------------------------------------------------------------------
__global__ __launch_bounds__(256, 3) void gemm_out(
    const short* __restrict__ ctx, const short* __restrict__ wt3,
    const float* __restrict__ bO, float* __restrict__ out) {
  __shared__ __align__(16) char Bl[2][16384];
  int wgid = blockIdx.x + 4 * blockIdx.y;
  int rr_ = wgid >> 3;
  int m0 = ((wgid & 7) * 16 + (rr_ >> 2)) * 128;
  int n0 = (rr_ & 3) * 128;
  int tid = threadIdx.x, lane = tid & 63, w = tid >> 6;
  int wr = w >> 1, wc = w & 1, g = lane >> 4, lr = lane & 15;
  int rowin = lane >> 3, sch8 = ((lane & 7) ^ rowin) * 8;

  const short* Ab = ctx + (size_t)(m0 + wr * 64 + lr) * D_ + g * 8;

  f32x4 acc[4][4] = {};
  bf16x8 acur[4][2], anxt[4][2];

#pragma unroll
  for (int j = 0; j < 4; ++j) {
    int e = w * 4 + j, row = e * 8 + rowin;
    gll16(wt3 + (size_t)(n0 + row) * D_ + sch8, &Bl[0][e * 1024]);
  }
#pragma unroll
  for (int i = 0; i < 4; ++i)
#pragma unroll
    for (int kk = 0; kk < 2; ++kk)
      acur[i][kk] = *(const bf16x8*)(Ab + (size_t)i * (16 * D_) + kk * 32);

#pragma unroll
  for (int it = 0; it < 8; ++it) {
    __syncthreads();
    if (it < 7) {
#pragma unroll
      for (int j = 0; j < 4; ++j) {
        int e = w * 4 + j, row = e * 8 + rowin;
        gll16(wt3 + (size_t)(n0 + row) * D_ + (it + 1) * 64 + sch8,
              &Bl[(it + 1) & 1][e * 1024]);
      }
#pragma unroll
      for (int i = 0; i < 4; ++i)
#pragma unroll
        for (int kk = 0; kk < 2; ++kk)
          anxt[i][kk] = *(const bf16x8*)(Ab + (size_t)i * (16 * D_) +
                                         (it + 1) * 64 + kk * 32);
    }
#pragma unroll
    for (int kk = 0; kk < 2; ++kk) {
      bf16x8 bf_[4];
#pragma unroll
      for (int i = 0; i < 4; ++i) {
        int row = wc * 64 + i * 16 + lr;
        bf_[i] = *(const bf16x8*)(&Bl[it & 1][row * 128 +
                                             (((kk * 4 + g) ^ (lr & 7)) << 4)]);
      }
#pragma unroll
      for (int mi = 0; mi < 4; ++mi)
#pragma unroll
        for (int nj = 0; nj < 4; ++nj)
          acc[mi][nj] = __builtin_amdgcn_mfma_f32_16x16x32_bf16(
              acur[mi][kk], bf_[nj], acc[mi][nj], 0, 0, 0);
    }
    if (it < 7) {
#pragma unroll
      for (int i = 0; i < 4; ++i)
#pragma unroll
        for (int kk = 0; kk < 2; ++kk) acur[i][kk] = anxt[i][kk];
    }
  }
#pragma unroll
  for (int mi = 0; mi < 4; ++mi) {
#pragma unroll
    for (int nj = 0; nj < 4; ++nj) {
      int n = n0 + wc * 64 + nj * 16 + lr;
      float bb = bO[n];
#pragma unroll
      for (int rr = 0; rr < 4; ++rr) {
        int m = m0 + wr * 64 + mi * 16 + g * 4 + rr;
        out[(size_t)m * D_ + n] = acc[mi][nj][rr] + bb;
      }
    }
  }
}

// --------------------------------------------------------------------------
extern "C" void kernel_launch(void* const* d_in, const int* in_sizes, int n_in,
                              void* d_out, int out_size, void* d_ws,
                              size_t ws_size, hipStream_t stream) {
  const float* query = (const float*)d_in[0];
  const float* key   = (const float*)d_in[1];
  const float* value = (const float*)d_in[2];
  const float* mask  = (const float*)d_in[3];
  // d_in[4..8]: edge/path inputs — bias is constant along the softmax axis,
  // so it cancels exactly; unused.
  const float* WQ = (const float*)d_in[9];
  const float* bQ = (const float*)d_in[10];
  const float* WK = (const float*)d_in[11];
  const float* bK = (const float*)d_in[12];
  const float* WV = (const float*)d_in[13];
  const float* bV = (const float*)d_in[14];
  const float* WO = (const float*)d_in[15];
  const float* bO = (const float*)d_in[16];

  short* ws  = (short*)d_ws;
  short* wt  = ws;
  short* q   = ws + 1048576;
  short* k   = q + 8388608;
  short* vt  = k + 8388608;
  short* ctx = vt + 8388608;   // total 34,603,008 shorts = 69.2 MB
  float* out = (float*)d_out;

  wt_kernel<<<dim3(16, 16, 4), 256, 0, stream>>>(WQ, WK, WV, WO, wt);
  gemm_qkv<<<dim3(4, 128, 3), 256, 0, stream>>>(query, key, value, wt,
                                                bQ, bK, bV, q, k, vt);
  attn_kernel<<<2048, 256, 0, stream>>>(q, k, vt, mask, ctx);
  gemm_out<<<dim3(4, 128), 256, 0, stream>>>(ctx, wt + 3 * 262144, bO, out);
}

// Round 5
// 133.010 us; speedup vs baseline: 1.4310x; 1.4310x over previous
//
#include <hip/hip_runtime.h>
#include <hip/hip_bf16.h>

// Problem sizes (fixed by the reference)
#define B_  32
#define L_  512
#define D_  512
#define H_  8
#define HD_ 64

typedef __attribute__((ext_vector_type(8))) short bf16x8;   // 8 bf16 (4 VGPRs)
typedef __attribute__((ext_vector_type(4))) short bf16x4;
typedef __attribute__((ext_vector_type(4))) float f32x4;

__device__ __forceinline__ short f2bf(float f) {
  union { float f; unsigned u; } x; x.f = f;
  unsigned r = x.u + 0x7FFFu + ((x.u >> 16) & 1u);   // RNE truncation
  return (short)(r >> 16);
}

// async global->LDS, 16B per lane; dest base must be wave-uniform (HW adds lane*16)
__device__ __forceinline__ void gll16(const void* g, void* l) {
  __builtin_amdgcn_global_load_lds(
      (const __attribute__((address_space(1))) unsigned int*)g,
      (__attribute__((address_space(3))) unsigned int*)l, 16, 0, 0);
}

// 8x f32 -> bf16x8 via v_cvt_pk_bf16_f32 (compiler lowers __float22bfloat162_rn)
__device__ __forceinline__ bf16x8 cvt8(f32x4 a, f32x4 b) {
  union { __hip_bfloat162 h[4]; bf16x8 v; } u;
  u.h[0] = __float22bfloat162_rn(float2{a[0], a[1]});
  u.h[1] = __float22bfloat162_rn(float2{a[2], a[3]});
  u.h[2] = __float22bfloat162_rn(float2{b[0], b[1]});
  u.h[3] = __float22bfloat162_rn(float2{b[2], b[3]});
  return u.v;
}

// same-wave LDS write->read ordering fence (rule 18: sched_barrier after asm waitcnt)
#define DS_FENCE() do { asm volatile("s_waitcnt lgkmcnt(0)" ::: "memory"); \
                        __builtin_amdgcn_sched_barrier(0); } while (0)

// --------------------------------------------------------------------------
// Weight transpose + convert: wt[w][n][k] = bf16(W_w[k][n]), w = 0..3
// --------------------------------------------------------------------------
__global__ __launch_bounds__(256) void wt_kernel(
    const float* __restrict__ WQ, const float* __restrict__ WK,
    const float* __restrict__ WV, const float* __restrict__ WO,
    short* __restrict__ wt) {
  __shared__ float tile[32][33];
  int wz = blockIdx.z;
  const float* W = (wz == 0) ? WQ : (wz == 1) ? WK : (wz == 2) ? WV : WO;
  int k0 = blockIdx.y * 32, n0 = blockIdx.x * 32;
  int tr = threadIdx.x >> 5, tc = threadIdx.x & 31;
#pragma unroll
  for (int i = 0; i < 4; ++i)
    tile[tr + i * 8][tc] = W[(size_t)(k0 + tr + i * 8) * D_ + n0 + tc];
  __syncthreads();
#pragma unroll
  for (int i = 0; i < 4; ++i)
    wt[((size_t)wz * D_ + n0 + tr + i * 8) * D_ + k0 + tc] =
        f2bf(tile[tc][tr + i * 8]);
}

// --------------------------------------------------------------------------
// QKV projection GEMM — attn-recipe pipeline (the structure that took attn
// 129->~30us): both tiles in LDS, double-buffered, BK=32; next tile's
// global_load_lds issued BEFORE this tile's compute; ONE barrier per K-step,
// so its vmcnt(0) drain waits only on loads that are a full compute-phase old.
// LDS: A f32 2x16KB + B bf16 2x8KB = 48KB -> 3 blocks/CU (12 waves).
// Swizzles give quarter-wave 2-way LDS access (free, m136).
// Output layouts: Q,K -> [b,h,l,hd] bf16; V -> [b,h,hd,l] bf16.
// --------------------------------------------------------------------------
__global__ __launch_bounds__(256, 3) void gemm_qkv(
    const float* __restrict__ Xq, const float* __restrict__ Xk,
    const float* __restrict__ Xv, const short* __restrict__ wt,
    const float* __restrict__ bQ, const float* __restrict__ bK,
    const float* __restrict__ bV,
    short* __restrict__ q_ws, short* __restrict__ k_ws,
    short* __restrict__ vt_ws) {
  __shared__ __align__(16) char lds[49152];   // A[2][16KB] | B[2][8KB]

  int mode = blockIdx.z;
  const float* A = (mode == 0) ? Xq : (mode == 1) ? Xk : Xv;
  const short* WT = wt + (size_t)mode * D_ * D_;
  const float* bias = (mode == 0) ? bQ : (mode == 1) ? bK : bV;

  // XCD swizzle: the 4 n-tiles sharing the same A-rows land on one XCD.
  int wgid = blockIdx.x + 4 * blockIdx.y;   // 0..511 (512 % 8 == 0: bijective)
  int rr_ = wgid >> 3;
  int m0 = ((wgid & 7) * 16 + (rr_ >> 2)) * 128;
  int n0 = (rr_ & 3) * 128;

  int tid = threadIdx.x, lane = tid & 63, w = tid >> 6;
  int wr = w >> 1, wc = w & 1, g = lane >> 4, lr = lane & 15;

  // staging lane constants
  int qa = lane >> 3, ca = (lane & 7) ^ qa;            // A: 8 rows x 128B /1KB
  int qb = lane >> 2, cb = (lane & 3) ^ ((lane >> 3) & 3);  // B: 16 rows x 64B

  // A f32 tile [128][32]: LDS row*128 + slot*16; slot s holds chunk s^(row&7)
  // B bf16 tile [128][32]: LDS row*64 + slot*16; slot s holds chunk s^((row>>1)&3)
  auto stage = [&](int ks, int bs) {
    char* Ab = lds + bs * 16384;
    char* Bb = lds + 32768 + bs * 8192;
#pragma unroll
    for (int j = 0; j < 4; ++j) {
      int e = w * 4 + j, row = e * 8 + qa;
      gll16(A + (size_t)(m0 + row) * D_ + ks * 32 + ca * 4, Ab + e * 1024);
    }
#pragma unroll
    for (int j = 0; j < 2; ++j) {
      int e = w * 2 + j, row = e * 16 + qb;
      gll16(WT + (size_t)(n0 + row) * D_ + ks * 32 + cb * 8, Bb + e * 1024);
    }
  };

  stage(0, 0);
  __syncthreads();   // prologue drain (only cold one)

  f32x4 acc[4][4] = {};
#pragma unroll
  for (int ks = 0; ks < 16; ++ks) {
    if (ks < 15) stage(ks + 1, (ks + 1) & 1);   // issue-early (T14)
    const char* Ab = lds + (ks & 1) * 16384;
    const char* Bb = lds + 32768 + (ks & 1) * 8192;
    bf16x8 af[4], bf_[4];
#pragma unroll
    for (int i = 0; i < 4; ++i) {
      int row = wr * 64 + i * 16 + lr;          // row & 7 == lr & 7
      f32x4 lo = *(const f32x4*)(Ab + row * 128 + (((2 * g) ^ (lr & 7)) << 4));
      f32x4 hi = *(const f32x4*)(Ab + row * 128 + (((2 * g + 1) ^ (lr & 7)) << 4));
      af[i] = cvt8(lo, hi);
    }
#pragma unroll
    for (int i = 0; i < 4; ++i) {
      int row = wc * 64 + i * 16 + lr;          // (row>>1)&3 == (lr>>1)&3
      bf_[i] = *(const bf16x8*)(Bb + row * 64 + ((g ^ ((lr >> 1) & 3)) << 4));
    }
#pragma unroll
    for (int mi = 0; mi < 4; ++mi)
#pragma unroll
      for (int nj = 0; nj < 4; ++nj)
        acc[mi][nj] = __builtin_amdgcn_mfma_f32_16x16x32_bf16(
            af[mi], bf_[nj], acc[mi][nj], 0, 0, 0);
    __syncthreads();   // drains: my reads (WAR) + next-tile stage (one phase old)
  }

  // Epilogue. C layout: row = g*4 + rr, col = lr (m89-verified).
#pragma unroll
  for (int mi = 0; mi < 4; ++mi) {
#pragma unroll
    for (int nj = 0; nj < 4; ++nj) {
      int n = n0 + wc * 64 + nj * 16 + lr;
      float bb = bias[n];
      int h = n >> 6, hd = n & 63;
#pragma unroll
      for (int rr = 0; rr < 4; ++rr) {
        int m = m0 + wr * 64 + mi * 16 + g * 4 + rr;
        int b = m >> 9, l = m & 511;
        short v = f2bf(acc[mi][nj][rr] + bb);
        if (mode == 0)
          q_ws[(((size_t)b * H_ + h) * L_ + l) * HD_ + hd] = v;
        else if (mode == 1)
          k_ws[(((size_t)b * H_ + h) * L_ + l) * HD_ + hd] = v;
        else
          vt_ws[(((size_t)b * H_ + h) * HD_ + hd) * L_ + l] = v;
      }
    }
  }
}

// --------------------------------------------------------------------------
// Attention, flash-style: block = 64 q-rows of one (b,h); 4 waves x 16 rows.
// 8 chunks of 64 keys; K/V chunk staged in LDS via global_load_lds (shared by
// all 4 waves, double-buffered, XOR-swizzled via pre-swizzled source), online
// softmax (small register state). LDS: K 2x8KB | V^T 2x8KB | P 4x2KB = 40KB.
// --------------------------------------------------------------------------
__global__ __launch_bounds__(256, 4) void attn_kernel(
    const short* __restrict__ q_ws, const short* __restrict__ k_ws,
    const short* __restrict__ vt_ws, const float* __restrict__ mask,
    short* __restrict__ ctx_ws) {
  __shared__ __align__(16) char lds[40960];
  int wg = blockIdx.x;                            // 2048 blocks, 2048%8==0
  int bh   = (wg & 7) * 32 + (wg >> 6);           // XCD-bijective: 32 heads/XCD
  int qblk = (wg >> 3) & 7;
  int b = bh >> 3, h = bh & 7;
  int tid = threadIdx.x, lane = tid & 63, w = tid >> 6;
  int g = lane >> 4, lr = lane & 15;
  char* Pl = lds + 32768 + w * 2048;              // per-wave P tile 16x64 bf16
  int qbase = qblk * 64 + w * 16;

  const short* Qh  = q_ws  + (size_t)bh * (L_ * HD_);
  const short* Kh  = k_ws  + (size_t)bh * (L_ * HD_);
  const short* VTh = vt_ws + (size_t)bh * (HD_ * L_);
  const float* mrow = mask + (size_t)b * L_;

  // Q fragments (A-operand): row = lr, k = g*8+j, two hd-halves
  bf16x8 aq0 = *(const bf16x8*)(Qh + (size_t)(qbase + lr) * HD_ + g * 8);
  bf16x8 aq1 = *(const bf16x8*)(Qh + (size_t)(qbase + lr) * HD_ + 32 + g * 8);

  // staging lane constants: 1KB issue = 8 rows x 128B; slot s holds chunk s^row
  int rowin = lane >> 3;
  int sch8 = ((lane & 7) ^ rowin) * 8;   // pre-swizzled source offset (shorts)

  // prologue: stage chunk 0 into buffer 0
#pragma unroll
  for (int j = 0; j < 2; ++j) {
    int e = w * 2 + j, row = e * 8 + rowin;
    gll16(Kh + (size_t)row * HD_ + sch8, lds + e * 1024);
    gll16(VTh + (size_t)row * L_ + sch8, lds + 16384 + e * 1024);
  }
  __syncthreads();

  f32x4 c[4] = {};
  float m[4] = {-1e30f, -1e30f, -1e30f, -1e30f};
  float sum[4] = {0.f, 0.f, 0.f, 0.f};

  for (int ch = 0; ch < 8; ++ch) {
    const char* Kb = lds + (ch & 1) * 8192;
    const char* Vb = lds + 16384 + (ch & 1) * 8192;
    if (ch < 7) {  // issue next chunk's stage first: overlaps this compute
      char* Kn = lds + ((ch + 1) & 1) * 8192;
      char* Vn = lds + 16384 + ((ch + 1) & 1) * 8192;
#pragma unroll
      for (int j = 0; j < 2; ++j) {
        int e = w * 2 + j, row = e * 8 + rowin;
        gll16(Kh + ((size_t)(ch + 1) * 64 + row) * HD_ + sch8, Kn + e * 1024);
        gll16(VTh + (size_t)row * L_ + (ch + 1) * 64 + sch8, Vn + e * 1024);
      }
    }
    float mb[4];
#pragma unroll
    for (int kt = 0; kt < 4; ++kt)
      mb[kt] = (1.0f - mrow[ch * 64 + kt * 16 + lr]) * -1e9f;

    // ---- QK^T for this chunk: s[4] = 16 q-rows x 64 keys ----
    f32x4 s[4];
#pragma unroll
    for (int kt = 0; kt < 4; ++kt) {
      int row = kt * 16 + lr;                      // row & 7 == lr & 7
      bf16x8 bk0 = *(const bf16x8*)(Kb + row * 128 + ((g ^ (lr & 7)) << 4));
      bf16x8 bk1 = *(const bf16x8*)(Kb + row * 128 + (((4 + g) ^ (lr & 7)) << 4));
      f32x4 a = {0.f, 0.f, 0.f, 0.f};
      a = __builtin_amdgcn_mfma_f32_16x16x32_bf16(aq0, bk0, a, 0, 0, 0);
      a = __builtin_amdgcn_mfma_f32_16x16x32_bf16(aq1, bk1, a, 0, 0, 0);
#pragma unroll
      for (int rr = 0; rr < 4; ++rr) a[rr] = a[rr] * 0.125f + mb[kt];
      s[kt] = a;
    }

    // ---- online softmax update (rows g*4+rr; cols lr+16*kt) ----
    float pmax[4], scl[4];
#pragma unroll
    for (int rr = 0; rr < 4; ++rr)
      pmax[rr] = fmaxf(fmaxf(s[0][rr], s[1][rr]), fmaxf(s[2][rr], s[3][rr]));
#pragma unroll
    for (int off = 1; off < 16; off <<= 1)
#pragma unroll
      for (int rr = 0; rr < 4; ++rr)
        pmax[rr] = fmaxf(pmax[rr], __shfl_xor(pmax[rr], off, 64));
#pragma unroll
    for (int rr = 0; rr < 4; ++rr) {
      float mn = fmaxf(m[rr], pmax[rr]);
      scl[rr] = __expf(m[rr] - mn);
      m[rr] = mn;
      sum[rr] *= scl[rr];
    }
#pragma unroll
    for (int nt = 0; nt < 4; ++nt)
#pragma unroll
      for (int rr = 0; rr < 4; ++rr) c[nt][rr] *= scl[rr];

    // P -> wave-private LDS tile (XOR-swizzled rows of 128B)
#pragma unroll
    for (int kt = 0; kt < 4; ++kt) {
      int col2 = (kt * 16 + lr) * 2;
#pragma unroll
      for (int rr = 0; rr < 4; ++rr) {
        float p = __expf(s[kt][rr] - m[rr]);
        sum[rr] += p;
        int row = g * 4 + rr;
        *(short*)(Pl + row * 128 + (col2 ^ ((row & 7) << 4))) = f2bf(p);
      }
    }
    DS_FENCE();   // own-wave P writes visible before transposed reads

    // ---- PV accumulate: c += P(16x64) @ V(64x64) ----
#pragma unroll
    for (int kk = 0; kk < 2; ++kk) {
      bf16x8 ap = *(const bf16x8*)(Pl + lr * 128 +
                                   (((kk * 4 + g) ^ (lr & 7)) << 4));
#pragma unroll
      for (int nt = 0; nt < 4; ++nt) {
        int row = nt * 16 + lr;
        bf16x8 bv = *(const bf16x8*)(Vb + row * 128 +
                                     (((kk * 4 + g) ^ (lr & 7)) << 4));
        c[nt] = __builtin_amdgcn_mfma_f32_16x16x32_bf16(ap, bv, c[nt], 0, 0, 0);
      }
    }
    DS_FENCE();   // P reads drained before next chunk's P writes (WAR)
    if (ch < 7) __syncthreads();   // next staged buffer ready for all waves
  }

  float inv[4];
#pragma unroll
  for (int off = 1; off < 16; off <<= 1)
#pragma unroll
    for (int rr = 0; rr < 4; ++rr) sum[rr] += __shfl_xor(sum[rr], off, 64);
#pragma unroll
  for (int rr = 0; rr < 4; ++rr) inv[rr] = 1.0f / sum[rr];

  // epilogue: ctx_ws[b][l][h][hd] (row-major [16384][512] for the out-GEMM)
#pragma unroll
  for (int nt = 0; nt < 4; ++nt) {
    int hd = nt * 16 + lr;
#pragma unroll
    for (int rr = 0; rr < 4; ++rr) {
      int qrow = qbase + g * 4 + rr;
      ctx_ws[(((size_t)b * L_ + qrow) * H_ + h) * HD_ + hd] =
          f2bf(c[nt][rr] * inv[rr]);
    }
  }
}

// --------------------------------------------------------------------------
// Output GEMM — same dbuf-BK32 pipeline, bf16 A (ctx).
// LDS: A 2x8KB + B 2x8KB = 32KB.
// --------------------------------------------------------------------------
__global__ __launch_bounds__(256, 3) void gemm_out(
    const short* __restrict__ ctx, const short* __restrict__ wt3,
    const float* __restrict__ bO, float* __restrict__ out) {
  __shared__ __align__(16) char lds[32768];   // A[2][8KB] | B[2][8KB]
  int wgid = blockIdx.x + 4 * blockIdx.y;
  int rr_ = wgid >> 3;
  int m0 = ((wgid & 7) * 16 + (rr_ >> 2)) * 128;
  int n0 = (rr_ & 3) * 128;
  int tid = threadIdx.x, lane = tid & 63, w = tid >> 6;
  int wr = w >> 1, wc = w & 1, g = lane >> 4, lr = lane & 15;
  int qb = lane >> 2, cb = (lane & 3) ^ ((lane >> 3) & 3);  // 16 rows x 64B /1KB

  auto stage = [&](int ks, int bs) {
    char* Ab = lds + bs * 8192;
    char* Bb = lds + 16384 + bs * 8192;
#pragma unroll
    for (int j = 0; j < 2; ++j) {
      int e = w * 2 + j, row = e * 16 + qb;
      gll16(ctx + (size_t)(m0 + row) * D_ + ks * 32 + cb * 8, Ab + e * 1024);
      gll16(wt3 + (size_t)(n0 + row) * D_ + ks * 32 + cb * 8, Bb + e * 1024);
    }
  };

  stage(0, 0);
  __syncthreads();

  f32x4 acc[4][4] = {};
#pragma unroll
  for (int ks = 0; ks < 16; ++ks) {
    if (ks < 15) stage(ks + 1, (ks + 1) & 1);
    const char* Ab = lds + (ks & 1) * 8192;
    const char* Bb = lds + 16384 + (ks & 1) * 8192;
    bf16x8 af[4], bf_[4];
#pragma unroll
    for (int i = 0; i < 4; ++i) {
      int row = wr * 64 + i * 16 + lr;
      af[i] = *(const bf16x8*)(Ab + row * 64 + ((g ^ ((lr >> 1) & 3)) << 4));
    }
#pragma unroll
    for (int i = 0; i < 4; ++i) {
      int row = wc * 64 + i * 16 + lr;
      bf_[i] = *(const bf16x8*)(Bb + row * 64 + ((g ^ ((lr >> 1) & 3)) << 4));
    }
#pragma unroll
    for (int mi = 0; mi < 4; ++mi)
#pragma unroll
      for (int nj = 0; nj < 4; ++nj)
        acc[mi][nj] = __builtin_amdgcn_mfma_f32_16x16x32_bf16(
            af[mi], bf_[nj], acc[mi][nj], 0, 0, 0);
    __syncthreads();
  }
#pragma unroll
  for (int mi = 0; mi < 4; ++mi) {
#pragma unroll
    for (int nj = 0; nj < 4; ++nj) {
      int n = n0 + wc * 64 + nj * 16 + lr;
      float bb = bO[n];
#pragma unroll
      for (int rr = 0; rr < 4; ++rr) {
        int m = m0 + wr * 64 + mi * 16 + g * 4 + rr;
        out[(size_t)m * D_ + n] = acc[mi][nj][rr] + bb;
      }
    }
  }
}

// --------------------------------------------------------------------------
extern "C" void kernel_launch(void* const* d_in, const int* in_sizes, int n_in,
                              void* d_out, int out_size, void* d_ws,
                              size_t ws_size, hipStream_t stream) {
  const float* query = (const float*)d_in[0];
  const float* key   = (const float*)d_in[1];
  const float* value = (const float*)d_in[2];
  const float* mask  = (const float*)d_in[3];
  // d_in[4..8]: edge/path inputs — bias is constant along the softmax axis,
  // so it cancels exactly; unused.
  const float* WQ = (const float*)d_in[9];
  const float* bQ = (const float*)d_in[10];
  const float* WK = (const float*)d_in[11];
  const float* bK = (const float*)d_in[12];
  const float* WV = (const float*)d_in[13];
  const float* bV = (const float*)d_in[14];
  const float* WO = (const float*)d_in[15];
  const float* bO = (const float*)d_in[16];

  short* ws  = (short*)d_ws;
  short* wt  = ws;
  short* q   = ws + 1048576;
  short* k   = q + 8388608;
  short* vt  = k + 8388608;
  short* ctx = vt + 8388608;   // total 34,603,008 shorts = 69.2 MB
  float* out = (float*)d_out;

  wt_kernel<<<dim3(16, 16, 4), 256, 0, stream>>>(WQ, WK, WV, WO, wt);
  gemm_qkv<<<dim3(4, 128, 3), 256, 0, stream>>>(query, key, value, wt,
                                                bQ, bK, bV, q, k, vt);
  attn_kernel<<<2048, 256, 0, stream>>>(q, k, vt, mask, ctx);
  gemm_out<<<dim3(4, 128), 256, 0, stream>>>(ctx, wt + 3 * 262144, bO, out);
}

// Round 6
// 130.691 us; speedup vs baseline: 1.4564x; 1.0177x over previous
//
#include <hip/hip_runtime.h>
#include <hip/hip_bf16.h>

// Problem sizes (fixed by the reference)
#define B_  32
#define L_  512
#define D_  512
#define H_  8
#define HD_ 64

typedef __attribute__((ext_vector_type(8))) short bf16x8;   // 8 bf16 (4 VGPRs)
typedef __attribute__((ext_vector_type(4))) short bf16x4;
typedef __attribute__((ext_vector_type(4))) float f32x4;

__device__ __forceinline__ short f2bf(float f) {
  union { float f; unsigned u; } x; x.f = f;
  unsigned r = x.u + 0x7FFFu + ((x.u >> 16) & 1u);   // RNE truncation
  return (short)(r >> 16);
}

// async global->LDS, 16B per lane; dest base must be wave-uniform (HW adds lane*16)
__device__ __forceinline__ void gll16(const void* g, void* l) {
  __builtin_amdgcn_global_load_lds(
      (const __attribute__((address_space(1))) unsigned int*)g,
      (__attribute__((address_space(3))) unsigned int*)l, 16, 0, 0);
}

// 8x f32 -> bf16x8 via v_cvt_pk_bf16_f32 (compiler lowers __float22bfloat162_rn)
__device__ __forceinline__ bf16x8 cvt8(f32x4 a, f32x4 b) {
  union { __hip_bfloat162 h[4]; bf16x8 v; } u;
  u.h[0] = __float22bfloat162_rn(float2{a[0], a[1]});
  u.h[1] = __float22bfloat162_rn(float2{a[2], a[3]});
  u.h[2] = __float22bfloat162_rn(float2{b[0], b[1]});
  u.h[3] = __float22bfloat162_rn(float2{b[2], b[3]});
  return u.v;
}

// same-wave LDS write->read ordering fence (rule 18: sched_barrier after asm waitcnt)
#define DS_FENCE() do { asm volatile("s_waitcnt lgkmcnt(0)" ::: "memory"); \
                        __builtin_amdgcn_sched_barrier(0); } while (0)

// --------------------------------------------------------------------------
// Weight transpose + convert: wt[w][n][k] = bf16(W_w[k][n]), w = 0..3
// --------------------------------------------------------------------------
__global__ __launch_bounds__(256) void wt_kernel(
    const float* __restrict__ WQ, const float* __restrict__ WK,
    const float* __restrict__ WV, const float* __restrict__ WO,
    short* __restrict__ wt) {
  __shared__ float tile[32][33];
  int wz = blockIdx.z;
  const float* W = (wz == 0) ? WQ : (wz == 1) ? WK : (wz == 2) ? WV : WO;
  int k0 = blockIdx.y * 32, n0 = blockIdx.x * 32;
  int tr = threadIdx.x >> 5, tc = threadIdx.x & 31;
#pragma unroll
  for (int i = 0; i < 4; ++i)
    tile[tr + i * 8][tc] = W[(size_t)(k0 + tr + i * 8) * D_ + n0 + tc];
  __syncthreads();
#pragma unroll
  for (int i = 0; i < 4; ++i)
    wt[((size_t)wz * D_ + n0 + tr + i * 8) * D_ + k0 + tc] =
        f2bf(tile[tc][tr + i * 8]);
}

// --------------------------------------------------------------------------
// QKV projection GEMM — 64x128 tile for OCCUPANCY (m114: resident-block
// overlap is what hides the 2-phase barrier drain). Single-buffer m97 shape,
// BK=64, R3's *measured-conflict-free* swizzles (A: 256B rows/16 slots,
// B: 128B rows/8 slots). acc 2x4 -> 32 AGPR. LDS 32KB -> 4-5 blocks/CU.
// Output layouts: Q,K -> [b,h,l,hd] bf16; V -> [b,h,hd,l] bf16.
// --------------------------------------------------------------------------
__global__ __launch_bounds__(256, 4) void gemm_qkv(
    const float* __restrict__ Xq, const float* __restrict__ Xk,
    const float* __restrict__ Xv, const short* __restrict__ wt,
    const float* __restrict__ bQ, const float* __restrict__ bK,
    const float* __restrict__ bV,
    short* __restrict__ q_ws, short* __restrict__ k_ws,
    short* __restrict__ vt_ws) {
  __shared__ __align__(16) char lds[32768];   // A f32 [64][256B] | B bf16 [128][128B]
  char* Al = lds;
  char* Bl = lds + 16384;

  int mode = blockIdx.z;
  const float* A = (mode == 0) ? Xq : (mode == 1) ? Xk : Xv;
  const short* WT = wt + (size_t)mode * D_ * D_;
  const float* bias = (mode == 0) ? bQ : (mode == 1) ? bK : bV;

  // XCD swizzle: 1024 blocks/mode; each XCD gets 32 consecutive m-tiles x 4
  // n-tiles (same map across modes -> X rows shared in one XCD's L2).
  int wgid = blockIdx.x + 4 * blockIdx.y;   // 0..1023, 1024 % 8 == 0
  int xcd = wgid & 7, idx = wgid >> 3;
  int m0 = (xcd * 32 + (idx >> 2)) * 64;
  int n0 = (idx & 3) * 128;

  int tid = threadIdx.x, lane = tid & 63, w = tid >> 6;
  int wr = w >> 1, wc = w & 1, g = lane >> 4, lr = lane & 15;

  f32x4 acc[2][4] = {};

#pragma unroll
  for (int ks = 0; ks < 8; ++ks) {
    __syncthreads();   // WAR: prior step's reads done before DMA overwrite
    // stage A 16KB: 4 issues/wave; issue e = rows e*4..e*4+3 x 16 slots;
    // slot s of row holds f32-chunk s ^ (row&15)   [R3-proven pattern]
#pragma unroll
    for (int j = 0; j < 4; ++j) {
      int e = w * 4 + j;
      int row = e * 4 + (lane >> 4);
      int chunk = (lane & 15) ^ (row & 15);
      gll16(A + (size_t)(m0 + row) * D_ + ks * 64 + chunk * 4, Al + e * 1024);
    }
    // stage B 16KB: 4 issues/wave; issue e = rows e*8..e*8+7 x 8 slots;
    // slot s holds bf16-chunk s ^ (row&7)          [R3-proven pattern]
#pragma unroll
    for (int j = 0; j < 4; ++j) {
      int e = w * 4 + j;
      int row = e * 8 + (lane >> 3);
      int chunk = (lane & 7) ^ (lane >> 3);
      gll16(WT + (size_t)(n0 + row) * D_ + ks * 64 + chunk * 8, Bl + e * 1024);
    }
    __syncthreads();   // drain: tiles ready (covered by other resident blocks)
#pragma unroll
    for (int kk = 0; kk < 2; ++kk) {
      bf16x8 af[2], bf_[4];
#pragma unroll
      for (int i = 0; i < 2; ++i) {
        int row = wr * 32 + i * 16 + lr;            // row & 15 == lr
        int o0 = ((kk * 8 + g * 2) ^ lr) << 4;
        int o1 = ((kk * 8 + g * 2 + 1) ^ lr) << 4;
        f32x4 lo = *(const f32x4*)(Al + row * 256 + o0);
        f32x4 hi = *(const f32x4*)(Al + row * 256 + o1);
        af[i] = cvt8(lo, hi);
      }
#pragma unroll
      for (int i = 0; i < 4; ++i) {
        int row = wc * 64 + i * 16 + lr;            // row & 7 == lr & 7
        bf_[i] = *(const bf16x8*)(Bl + row * 128 +
                                  (((kk * 4 + g) ^ (lr & 7)) << 4));
      }
#pragma unroll
      for (int mi = 0; mi < 2; ++mi)
#pragma unroll
        for (int nj = 0; nj < 4; ++nj)
          acc[mi][nj] = __builtin_amdgcn_mfma_f32_16x16x32_bf16(
              af[mi], bf_[nj], acc[mi][nj], 0, 0, 0);
    }
  }

  // Epilogue. C layout: row = g*4 + rr, col = lr (m89-verified).
#pragma unroll
  for (int mi = 0; mi < 2; ++mi) {
#pragma unroll
    for (int nj = 0; nj < 4; ++nj) {
      int n = n0 + wc * 64 + nj * 16 + lr;
      float bb = bias[n];
      int h = n >> 6, hd = n & 63;
#pragma unroll
      for (int rr = 0; rr < 4; ++rr) {
        int m = m0 + wr * 32 + mi * 16 + g * 4 + rr;
        int b = m >> 9, l = m & 511;
        short v = f2bf(acc[mi][nj][rr] + bb);
        if (mode == 0)
          q_ws[(((size_t)b * H_ + h) * L_ + l) * HD_ + hd] = v;
        else if (mode == 1)
          k_ws[(((size_t)b * H_ + h) * L_ + l) * HD_ + hd] = v;
        else
          vt_ws[(((size_t)b * H_ + h) * HD_ + hd) * L_ + l] = v;
      }
    }
  }
}

// --------------------------------------------------------------------------
// Attention, flash-style: block = 64 q-rows of one (b,h); 4 waves x 16 rows.
// 8 chunks of 64 keys; K/V chunk staged in LDS via global_load_lds (shared by
// all 4 waves, double-buffered, XOR-swizzled via pre-swizzled source), online
// softmax (small register state). LDS: K 2x8KB | V^T 2x8KB | P 4x2KB = 40KB.
// --------------------------------------------------------------------------
__global__ __launch_bounds__(256, 4) void attn_kernel(
    const short* __restrict__ q_ws, const short* __restrict__ k_ws,
    const short* __restrict__ vt_ws, const float* __restrict__ mask,
    short* __restrict__ ctx_ws) {
  __shared__ __align__(16) char lds[40960];
  int wg = blockIdx.x;                            // 2048 blocks, 2048%8==0
  int bh   = (wg & 7) * 32 + (wg >> 6);           // XCD-bijective: 32 heads/XCD
  int qblk = (wg >> 3) & 7;
  int b = bh >> 3, h = bh & 7;
  int tid = threadIdx.x, lane = tid & 63, w = tid >> 6;
  int g = lane >> 4, lr = lane & 15;
  char* Pl = lds + 32768 + w * 2048;              // per-wave P tile 16x64 bf16
  int qbase = qblk * 64 + w * 16;

  const short* Qh  = q_ws  + (size_t)bh * (L_ * HD_);
  const short* Kh  = k_ws  + (size_t)bh * (L_ * HD_);
  const short* VTh = vt_ws + (size_t)bh * (HD_ * L_);
  const float* mrow = mask + (size_t)b * L_;

  // Q fragments (A-operand): row = lr, k = g*8+j, two hd-halves
  bf16x8 aq0 = *(const bf16x8*)(Qh + (size_t)(qbase + lr) * HD_ + g * 8);
  bf16x8 aq1 = *(const bf16x8*)(Qh + (size_t)(qbase + lr) * HD_ + 32 + g * 8);

  // staging lane constants: 1KB issue = 8 rows x 128B; slot s holds chunk s^row
  int rowin = lane >> 3;
  int sch8 = ((lane & 7) ^ rowin) * 8;   // pre-swizzled source offset (shorts)

  // prologue: stage chunk 0 into buffer 0
#pragma unroll
  for (int j = 0; j < 2; ++j) {
    int e = w * 2 + j, row = e * 8 + rowin;
    gll16(Kh + (size_t)row * HD_ + sch8, lds + e * 1024);
    gll16(VTh + (size_t)row * L_ + sch8, lds + 16384 + e * 1024);
  }
  __syncthreads();

  f32x4 c[4] = {};
  float m[4] = {-1e30f, -1e30f, -1e30f, -1e30f};
  float sum[4] = {0.f, 0.f, 0.f, 0.f};

  for (int ch = 0; ch < 8; ++ch) {
    const char* Kb = lds + (ch & 1) * 8192;
    const char* Vb = lds + 16384 + (ch & 1) * 8192;
    if (ch < 7) {  // issue next chunk's stage first: overlaps this compute
      char* Kn = lds + ((ch + 1) & 1) * 8192;
      char* Vn = lds + 16384 + ((ch + 1) & 1) * 8192;
#pragma unroll
      for (int j = 0; j < 2; ++j) {
        int e = w * 2 + j, row = e * 8 + rowin;
        gll16(Kh + ((size_t)(ch + 1) * 64 + row) * HD_ + sch8, Kn + e * 1024);
        gll16(VTh + (size_t)row * L_ + (ch + 1) * 64 + sch8, Vn + e * 1024);
      }
    }
    float mb[4];
#pragma unroll
    for (int kt = 0; kt < 4; ++kt)
      mb[kt] = (1.0f - mrow[ch * 64 + kt * 16 + lr]) * -1e9f;

    // ---- QK^T for this chunk: s[4] = 16 q-rows x 64 keys ----
    f32x4 s[4];
#pragma unroll
    for (int kt = 0; kt < 4; ++kt) {
      int row = kt * 16 + lr;                      // row & 7 == lr & 7
      bf16x8 bk0 = *(const bf16x8*)(Kb + row * 128 + ((g ^ (lr & 7)) << 4));
      bf16x8 bk1 = *(const bf16x8*)(Kb + row * 128 + (((4 + g) ^ (lr & 7)) << 4));
      f32x4 a = {0.f, 0.f, 0.f, 0.f};
      a = __builtin_amdgcn_mfma_f32_16x16x32_bf16(aq0, bk0, a, 0, 0, 0);
      a = __builtin_amdgcn_mfma_f32_16x16x32_bf16(aq1, bk1, a, 0, 0, 0);
#pragma unroll
      for (int rr = 0; rr < 4; ++rr) a[rr] = a[rr] * 0.125f + mb[kt];
      s[kt] = a;
    }

    // ---- online softmax update (rows g*4+rr; cols lr+16*kt) ----
    float pmax[4], scl[4];
#pragma unroll
    for (int rr = 0; rr < 4; ++rr)
      pmax[rr] = fmaxf(fmaxf(s[0][rr], s[1][rr]), fmaxf(s[2][rr], s[3][rr]));
#pragma unroll
    for (int off = 1; off < 16; off <<= 1)
#pragma unroll
      for (int rr = 0; rr < 4; ++rr)
        pmax[rr] = fmaxf(pmax[rr], __shfl_xor(pmax[rr], off, 64));
#pragma unroll
    for (int rr = 0; rr < 4; ++rr) {
      float mn = fmaxf(m[rr], pmax[rr]);
      scl[rr] = __expf(m[rr] - mn);
      m[rr] = mn;
      sum[rr] *= scl[rr];
    }
#pragma unroll
    for (int nt = 0; nt < 4; ++nt)
#pragma unroll
      for (int rr = 0; rr < 4; ++rr) c[nt][rr] *= scl[rr];

    // P -> wave-private LDS tile (XOR-swizzled rows of 128B)
#pragma unroll
    for (int kt = 0; kt < 4; ++kt) {
      int col2 = (kt * 16 + lr) * 2;
#pragma unroll
      for (int rr = 0; rr < 4; ++rr) {
        float p = __expf(s[kt][rr] - m[rr]);
        sum[rr] += p;
        int row = g * 4 + rr;
        *(short*)(Pl + row * 128 + (col2 ^ ((row & 7) << 4))) = f2bf(p);
      }
    }
    DS_FENCE();   // own-wave P writes visible before transposed reads

    // ---- PV accumulate: c += P(16x64) @ V(64x64) ----
#pragma unroll
    for (int kk = 0; kk < 2; ++kk) {
      bf16x8 ap = *(const bf16x8*)(Pl + lr * 128 +
                                   (((kk * 4 + g) ^ (lr & 7)) << 4));
#pragma unroll
      for (int nt = 0; nt < 4; ++nt) {
        int row = nt * 16 + lr;
        bf16x8 bv = *(const bf16x8*)(Vb + row * 128 +
                                     (((kk * 4 + g) ^ (lr & 7)) << 4));
        c[nt] = __builtin_amdgcn_mfma_f32_16x16x32_bf16(ap, bv, c[nt], 0, 0, 0);
      }
    }
    DS_FENCE();   // P reads drained before next chunk's P writes (WAR)
    if (ch < 7) __syncthreads();   // next staged buffer ready for all waves
  }

  float inv[4];
#pragma unroll
  for (int off = 1; off < 16; off <<= 1)
#pragma unroll
    for (int rr = 0; rr < 4; ++rr) sum[rr] += __shfl_xor(sum[rr], off, 64);
#pragma unroll
  for (int rr = 0; rr < 4; ++rr) inv[rr] = 1.0f / sum[rr];

  // epilogue: ctx_ws[b][l][h][hd] (row-major [16384][512] for the out-GEMM)
#pragma unroll
  for (int nt = 0; nt < 4; ++nt) {
    int hd = nt * 16 + lr;
#pragma unroll
    for (int rr = 0; rr < 4; ++rr) {
      int qrow = qbase + g * 4 + rr;
      ctx_ws[(((size_t)b * L_ + qrow) * H_ + h) * HD_ + hd] =
          f2bf(c[nt][rr] * inv[rr]);
    }
  }
}

// --------------------------------------------------------------------------
// Output GEMM — 64x128 tile, single-buffer, BK=64, all-bf16.
// LDS: A [64][128B] 8KB + B [128][128B] 16KB = 24KB -> 5-6 blocks/CU.
// --------------------------------------------------------------------------
__global__ __launch_bounds__(256, 4) void gemm_out(
    const short* __restrict__ ctx, const short* __restrict__ wt3,
    const float* __restrict__ bO, float* __restrict__ out) {
  __shared__ __align__(16) char lds[24576];
  char* Al = lds;
  char* Bl = lds + 8192;
  int wgid = blockIdx.x + 4 * blockIdx.y;   // 0..1023
  int xcd = wgid & 7, idx = wgid >> 3;
  int m0 = (xcd * 32 + (idx >> 2)) * 64;
  int n0 = (idx & 3) * 128;
  int tid = threadIdx.x, lane = tid & 63, w = tid >> 6;
  int wr = w >> 1, wc = w & 1, g = lane >> 4, lr = lane & 15;

  f32x4 acc[2][4] = {};

#pragma unroll
  for (int ks = 0; ks < 8; ++ks) {
    __syncthreads();
    // stage A 8KB: 2 issues/wave (rows e*8..e*8+7, 8 slots, chunk s^(row&7))
#pragma unroll
    for (int j = 0; j < 2; ++j) {
      int e = w * 2 + j;
      int row = e * 8 + (lane >> 3);
      int chunk = (lane & 7) ^ (lane >> 3);
      gll16(ctx + (size_t)(m0 + row) * D_ + ks * 64 + chunk * 8, Al + e * 1024);
    }
    // stage B 16KB: 4 issues/wave
#pragma unroll
    for (int j = 0; j < 4; ++j) {
      int e = w * 4 + j;
      int row = e * 8 + (lane >> 3);
      int chunk = (lane & 7) ^ (lane >> 3);
      gll16(wt3 + (size_t)(n0 + row) * D_ + ks * 64 + chunk * 8, Bl + e * 1024);
    }
    __syncthreads();
#pragma unroll
    for (int kk = 0; kk < 2; ++kk) {
      bf16x8 af[2], bf_[4];
#pragma unroll
      for (int i = 0; i < 2; ++i) {
        int row = wr * 32 + i * 16 + lr;            // row & 7 == lr & 7
        af[i] = *(const bf16x8*)(Al + row * 128 +
                                 (((kk * 4 + g) ^ (lr & 7)) << 4));
      }
#pragma unroll
      for (int i = 0; i < 4; ++i) {
        int row = wc * 64 + i * 16 + lr;
        bf_[i] = *(const bf16x8*)(Bl + row * 128 +
                                  (((kk * 4 + g) ^ (lr & 7)) << 4));
      }
#pragma unroll
      for (int mi = 0; mi < 2; ++mi)
#pragma unroll
        for (int nj = 0; nj < 4; ++nj)
          acc[mi][nj] = __builtin_amdgcn_mfma_f32_16x16x32_bf16(
              af[mi], bf_[nj], acc[mi][nj], 0, 0, 0);
    }
  }
#pragma unroll
  for (int mi = 0; mi < 2; ++mi) {
#pragma unroll
    for (int nj = 0; nj < 4; ++nj) {
      int n = n0 + wc * 64 + nj * 16 + lr;
      float bb = bO[n];
#pragma unroll
      for (int rr = 0; rr < 4; ++rr) {
        int m = m0 + wr * 32 + mi * 16 + g * 4 + rr;
        out[(size_t)m * D_ + n] = acc[mi][nj][rr] + bb;
      }
    }
  }
}

// --------------------------------------------------------------------------
extern "C" void kernel_launch(void* const* d_in, const int* in_sizes, int n_in,
                              void* d_out, int out_size, void* d_ws,
                              size_t ws_size, hipStream_t stream) {
  const float* query = (const float*)d_in[0];
  const float* key   = (const float*)d_in[1];
  const float* value = (const float*)d_in[2];
  const float* mask  = (const float*)d_in[3];
  // d_in[4..8]: edge/path inputs — bias is constant along the softmax axis,
  // so it cancels exactly; unused.
  const float* WQ = (const float*)d_in[9];
  const float* bQ = (const float*)d_in[10];
  const float* WK = (const float*)d_in[11];
  const float* bK = (const float*)d_in[12];
  const float* WV = (const float*)d_in[13];
  const float* bV = (const float*)d_in[14];
  const float* WO = (const float*)d_in[15];
  const float* bO = (const float*)d_in[16];

  short* ws  = (short*)d_ws;
  short* wt  = ws;
  short* q   = ws + 1048576;
  short* k   = q + 8388608;
  short* vt  = k + 8388608;
  short* ctx = vt + 8388608;   // total 34,603,008 shorts = 69.2 MB
  float* out = (float*)d_out;

  wt_kernel<<<dim3(16, 16, 4), 256, 0, stream>>>(WQ, WK, WV, WO, wt);
  gemm_qkv<<<dim3(4, 256, 3), 256, 0, stream>>>(query, key, value, wt,
                                                bQ, bK, bV, q, k, vt);
  attn_kernel<<<2048, 256, 0, stream>>>(q, k, vt, mask, ctx);
  gemm_out<<<dim3(4, 256), 256, 0, stream>>>(ctx, wt + 3 * 262144, bO, out);
}

// Round 7
// 129.904 us; speedup vs baseline: 1.4652x; 1.0061x over previous
//
#include <hip/hip_runtime.h>
#include <hip/hip_bf16.h>

// Problem sizes (fixed by the reference)
#define B_  32
#define L_  512
#define D_  512
#define H_  8
#define HD_ 64

typedef __attribute__((ext_vector_type(8))) short bf16x8;   // 8 bf16 (4 VGPRs)
typedef __attribute__((ext_vector_type(4))) short bf16x4;
typedef __attribute__((ext_vector_type(4))) float f32x4;

__device__ __forceinline__ short f2bf(float f) {
  union { float f; unsigned u; } x; x.f = f;
  unsigned r = x.u + 0x7FFFu + ((x.u >> 16) & 1u);   // RNE truncation
  return (short)(r >> 16);
}

// async global->LDS, 16B per lane; dest base must be wave-uniform (HW adds lane*16)
__device__ __forceinline__ void gll16(const void* g, void* l) {
  __builtin_amdgcn_global_load_lds(
      (const __attribute__((address_space(1))) unsigned int*)g,
      (__attribute__((address_space(3))) unsigned int*)l, 16, 0, 0);
}

// 8x f32 -> bf16x8 via v_cvt_pk_bf16_f32 (compiler lowers __float22bfloat162_rn)
__device__ __forceinline__ bf16x8 cvt8(f32x4 a, f32x4 b) {
  union { __hip_bfloat162 h[4]; bf16x8 v; } u;
  u.h[0] = __float22bfloat162_rn(float2{a[0], a[1]});
  u.h[1] = __float22bfloat162_rn(float2{a[2], a[3]});
  u.h[2] = __float22bfloat162_rn(float2{b[0], b[1]});
  u.h[3] = __float22bfloat162_rn(float2{b[2], b[3]});
  return u.v;
}

// same-wave LDS write->read ordering fence (rule 18: sched_barrier after asm waitcnt)
#define DS_FENCE() do { asm volatile("s_waitcnt lgkmcnt(0)" ::: "memory"); \
                        __builtin_amdgcn_sched_barrier(0); } while (0)
// counted vmcnt (T4): wait all but the N newest VMEM ops; compiler-level
// memory fence via clobber, instruction pinning via sched_barrier at call site
#define VMCNT6 asm volatile("s_waitcnt vmcnt(6)" ::: "memory")
#define VMCNT4 asm volatile("s_waitcnt vmcnt(4)" ::: "memory")
#define VMCNT0 asm volatile("s_waitcnt vmcnt(0)" ::: "memory")
#define SCHEDB __builtin_amdgcn_sched_barrier(0)

// --------------------------------------------------------------------------
// Weight transpose + convert: wt[w][n][k] = bf16(W_w[k][n]), w = 0..3
// --------------------------------------------------------------------------
__global__ __launch_bounds__(256) void wt_kernel(
    const float* __restrict__ WQ, const float* __restrict__ WK,
    const float* __restrict__ WV, const float* __restrict__ WO,
    short* __restrict__ wt) {
  __shared__ float tile[32][33];
  int wz = blockIdx.z;
  const float* W = (wz == 0) ? WQ : (wz == 1) ? WK : (wz == 2) ? WV : WO;
  int k0 = blockIdx.y * 32, n0 = blockIdx.x * 32;
  int tr = threadIdx.x >> 5, tc = threadIdx.x & 31;
#pragma unroll
  for (int i = 0; i < 4; ++i)
    tile[tr + i * 8][tc] = W[(size_t)(k0 + tr + i * 8) * D_ + n0 + tc];
  __syncthreads();
#pragma unroll
  for (int i = 0; i < 4; ++i)
    wt[((size_t)wz * D_ + n0 + tr + i * 8) * D_ + k0 + tc] =
        f2bf(tile[tc][tr + i * 8]);
}

// --------------------------------------------------------------------------
// QKV projection GEMM — counted-vmcnt pipeline (T3+T4): 3 LDS buffers,
// stage tile t+2 while computing tile t; end-of-step wait is vmcnt(6) (tile
// t+1 ready, tile t+2's 6 loads STAY IN FLIGHT across the raw s_barrier).
// This is the mechanism __syncthreads forbids (its drain is vmcnt(0)).
// 128x128 tile, BK=32, 16 steps, acc 4x4. LDS 72KB -> 2 blocks/CU (pipeline
// replaces TLP). Output: Q,K -> [b,h,l,hd] bf16; V -> [b,h,hd,l] bf16.
// --------------------------------------------------------------------------
__global__ __launch_bounds__(256, 2) void gemm_qkv(
    const float* __restrict__ Xq, const float* __restrict__ Xk,
    const float* __restrict__ Xv, const short* __restrict__ wt,
    const float* __restrict__ bQ, const float* __restrict__ bK,
    const float* __restrict__ bV,
    short* __restrict__ q_ws, short* __restrict__ k_ws,
    short* __restrict__ vt_ws) {
  __shared__ __align__(16) char lds[73728];  // A f32 3x16KB | B bf16 3x8KB

  int mode = blockIdx.z;
  const float* A = (mode == 0) ? Xq : (mode == 1) ? Xk : Xv;
  const short* WT = wt + (size_t)mode * D_ * D_;
  const float* bias = (mode == 0) ? bQ : (mode == 1) ? bK : bV;

  // XCD swizzle (R3-proven): 4 n-tiles sharing A-rows land on one XCD.
  int wgid = blockIdx.x + 4 * blockIdx.y;   // 0..511, 512 % 8 == 0: bijective
  int rr_ = wgid >> 3;
  int m0 = ((wgid & 7) * 16 + (rr_ >> 2)) * 128;
  int n0 = (rr_ & 3) * 128;

  int tid = threadIdx.x, lane = tid & 63, w = tid >> 6;
  int wr = w >> 1, wc = w & 1, g = lane >> 4, lr = lane & 15;

  // staging lane constants
  int ca = (lane & 7) ^ (lane >> 3);              // A: 8 rows x 128B per issue
  int cb = (lane & 3) ^ ((lane >> 2) & 3);        // B: 16 rows x 64B per issue

  // A f32 [128][32]: LDS row*128 + slot*16; slot s holds chunk s^(row&7)
  auto stageA = [&](int ks, int bi) {
    char* Ab = lds + bi * 16384;
#pragma unroll
    for (int j = 0; j < 4; ++j) {
      int e = w * 4 + j, row = e * 8 + (lane >> 3);
      gll16(A + (size_t)(m0 + row) * D_ + ks * 32 + ca * 4, Ab + e * 1024);
    }
  };
  // B bf16 [128][32]: LDS row*64 + slot*16; slot s holds chunk s^(row&3)
  auto stageB = [&](int ks, int bi) {
    char* Bb = lds + 49152 + bi * 8192;
#pragma unroll
    for (int j = 0; j < 2; ++j) {
      int e = w * 2 + j, row = e * 16 + (lane >> 2);
      gll16(WT + (size_t)(n0 + row) * D_ + ks * 32 + cb * 8, Bb + e * 1024);
    }
  };

  // prologue: tiles 0 and 1 in flight; wait tile 0 only (newest 6 keep flying)
  stageA(0, 0); stageB(0, 0);
  stageA(1, 1); stageB(1, 1);
  VMCNT6;
  __builtin_amdgcn_s_barrier();
  SCHEDB;

  f32x4 acc[4][4] = {};
#pragma unroll
  for (int t = 0; t < 16; ++t) {
    if (t < 14) {            // issue tile t+2 (6 gll16/wave), pinned first
      stageA(t + 2, (t + 2) % 3);
      stageB(t + 2, (t + 2) % 3);
      SCHEDB;
    }
    const char* Ab = lds + (t % 3) * 16384;
    const char* Bb = lds + 49152 + (t % 3) * 8192;
    bf16x8 af[4], bf_[4];
#pragma unroll
    for (int i = 0; i < 4; ++i) {
      int row = wr * 64 + i * 16 + lr;            // row & 7 == lr & 7
      f32x4 lo = *(const f32x4*)(Ab + row * 128 + (((2 * g) ^ (lr & 7)) << 4));
      f32x4 hi = *(const f32x4*)(Ab + row * 128 + (((2 * g + 1) ^ (lr & 7)) << 4));
      af[i] = cvt8(lo, hi);
    }
#pragma unroll
    for (int i = 0; i < 4; ++i) {
      int row = wc * 64 + i * 16 + lr;            // row & 3 == lr & 3
      bf_[i] = *(const bf16x8*)(Bb + row * 64 + ((g ^ (lr & 3)) << 4));
    }
    __builtin_amdgcn_s_setprio(1);
#pragma unroll
    for (int mi = 0; mi < 4; ++mi)
#pragma unroll
      for (int nj = 0; nj < 4; ++nj)
        acc[mi][nj] = __builtin_amdgcn_mfma_f32_16x16x32_bf16(
            af[mi], bf_[nj], acc[mi][nj], 0, 0, 0);
    __builtin_amdgcn_s_setprio(0);
    if (t < 15) {
      if (t < 14) { VMCNT6; }   // tile t+1 ready; tile t+2 stays in flight
      else       { VMCNT0; }    // last tile: nothing newer to protect
      __builtin_amdgcn_s_barrier();
      SCHEDB;
    }
  }

  // Epilogue. C layout: row = g*4 + rr, col = lr (m89-verified).
#pragma unroll
  for (int mi = 0; mi < 4; ++mi) {
#pragma unroll
    for (int nj = 0; nj < 4; ++nj) {
      int n = n0 + wc * 64 + nj * 16 + lr;
      float bb = bias[n];
      int h = n >> 6, hd = n & 63;
#pragma unroll
      for (int rr = 0; rr < 4; ++rr) {
        int m = m0 + wr * 64 + mi * 16 + g * 4 + rr;
        int b = m >> 9, l = m & 511;
        short v = f2bf(acc[mi][nj][rr] + bb);
        if (mode == 0)
          q_ws[(((size_t)b * H_ + h) * L_ + l) * HD_ + hd] = v;
        else if (mode == 1)
          k_ws[(((size_t)b * H_ + h) * L_ + l) * HD_ + hd] = v;
        else
          vt_ws[(((size_t)b * H_ + h) * HD_ + hd) * L_ + l] = v;
      }
    }
  }
}

// --------------------------------------------------------------------------
// Attention, flash-style (unchanged from R6; ~30us): block = 64 q-rows of one
// (b,h); 4 waves x 16 rows; K/V dbuf LDS via gll16; online softmax.
// --------------------------------------------------------------------------
__global__ __launch_bounds__(256, 4) void attn_kernel(
    const short* __restrict__ q_ws, const short* __restrict__ k_ws,
    const short* __restrict__ vt_ws, const float* __restrict__ mask,
    short* __restrict__ ctx_ws) {
  __shared__ __align__(16) char lds[40960];
  int wg = blockIdx.x;                            // 2048 blocks, 2048%8==0
  int bh   = (wg & 7) * 32 + (wg >> 6);           // XCD-bijective: 32 heads/XCD
  int qblk = (wg >> 3) & 7;
  int b = bh >> 3, h = bh & 7;
  int tid = threadIdx.x, lane = tid & 63, w = tid >> 6;
  int g = lane >> 4, lr = lane & 15;
  char* Pl = lds + 32768 + w * 2048;              // per-wave P tile 16x64 bf16
  int qbase = qblk * 64 + w * 16;

  const short* Qh  = q_ws  + (size_t)bh * (L_ * HD_);
  const short* Kh  = k_ws  + (size_t)bh * (L_ * HD_);
  const short* VTh = vt_ws + (size_t)bh * (HD_ * L_);
  const float* mrow = mask + (size_t)b * L_;

  bf16x8 aq0 = *(const bf16x8*)(Qh + (size_t)(qbase + lr) * HD_ + g * 8);
  bf16x8 aq1 = *(const bf16x8*)(Qh + (size_t)(qbase + lr) * HD_ + 32 + g * 8);

  int rowin = lane >> 3;
  int sch8 = ((lane & 7) ^ rowin) * 8;   // pre-swizzled source offset (shorts)

#pragma unroll
  for (int j = 0; j < 2; ++j) {
    int e = w * 2 + j, row = e * 8 + rowin;
    gll16(Kh + (size_t)row * HD_ + sch8, lds + e * 1024);
    gll16(VTh + (size_t)row * L_ + sch8, lds + 16384 + e * 1024);
  }
  __syncthreads();

  f32x4 c[4] = {};
  float m[4] = {-1e30f, -1e30f, -1e30f, -1e30f};
  float sum[4] = {0.f, 0.f, 0.f, 0.f};

  for (int ch = 0; ch < 8; ++ch) {
    const char* Kb = lds + (ch & 1) * 8192;
    const char* Vb = lds + 16384 + (ch & 1) * 8192;
    if (ch < 7) {  // issue next chunk's stage first: overlaps this compute
      char* Kn = lds + ((ch + 1) & 1) * 8192;
      char* Vn = lds + 16384 + ((ch + 1) & 1) * 8192;
#pragma unroll
      for (int j = 0; j < 2; ++j) {
        int e = w * 2 + j, row = e * 8 + rowin;
        gll16(Kh + ((size_t)(ch + 1) * 64 + row) * HD_ + sch8, Kn + e * 1024);
        gll16(VTh + (size_t)row * L_ + (ch + 1) * 64 + sch8, Vn + e * 1024);
      }
    }
    float mb[4];
#pragma unroll
    for (int kt = 0; kt < 4; ++kt)
      mb[kt] = (1.0f - mrow[ch * 64 + kt * 16 + lr]) * -1e9f;

    f32x4 s[4];
#pragma unroll
    for (int kt = 0; kt < 4; ++kt) {
      int row = kt * 16 + lr;                      // row & 7 == lr & 7
      bf16x8 bk0 = *(const bf16x8*)(Kb + row * 128 + ((g ^ (lr & 7)) << 4));
      bf16x8 bk1 = *(const bf16x8*)(Kb + row * 128 + (((4 + g) ^ (lr & 7)) << 4));
      f32x4 a = {0.f, 0.f, 0.f, 0.f};
      a = __builtin_amdgcn_mfma_f32_16x16x32_bf16(aq0, bk0, a, 0, 0, 0);
      a = __builtin_amdgcn_mfma_f32_16x16x32_bf16(aq1, bk1, a, 0, 0, 0);
#pragma unroll
      for (int rr = 0; rr < 4; ++rr) a[rr] = a[rr] * 0.125f + mb[kt];
      s[kt] = a;
    }

    float pmax[4], scl[4];
#pragma unroll
    for (int rr = 0; rr < 4; ++rr)
      pmax[rr] = fmaxf(fmaxf(s[0][rr], s[1][rr]), fmaxf(s[2][rr], s[3][rr]));
#pragma unroll
    for (int off = 1; off < 16; off <<= 1)
#pragma unroll
      for (int rr = 0; rr < 4; ++rr)
        pmax[rr] = fmaxf(pmax[rr], __shfl_xor(pmax[rr], off, 64));
#pragma unroll
    for (int rr = 0; rr < 4; ++rr) {
      float mn = fmaxf(m[rr], pmax[rr]);
      scl[rr] = __expf(m[rr] - mn);
      m[rr] = mn;
      sum[rr] *= scl[rr];
    }
#pragma unroll
    for (int nt = 0; nt < 4; ++nt)
#pragma unroll
      for (int rr = 0; rr < 4; ++rr) c[nt][rr] *= scl[rr];

#pragma unroll
    for (int kt = 0; kt < 4; ++kt) {
      int col2 = (kt * 16 + lr) * 2;
#pragma unroll
      for (int rr = 0; rr < 4; ++rr) {
        float p = __expf(s[kt][rr] - m[rr]);
        sum[rr] += p;
        int row = g * 4 + rr;
        *(short*)(Pl + row * 128 + (col2 ^ ((row & 7) << 4))) = f2bf(p);
      }
    }
    DS_FENCE();   // own-wave P writes visible before transposed reads

#pragma unroll
    for (int kk = 0; kk < 2; ++kk) {
      bf16x8 ap = *(const bf16x8*)(Pl + lr * 128 +
                                   (((kk * 4 + g) ^ (lr & 7)) << 4));
#pragma unroll
      for (int nt = 0; nt < 4; ++nt) {
        int row = nt * 16 + lr;
        bf16x8 bv = *(const bf16x8*)(Vb + row * 128 +
                                     (((kk * 4 + g) ^ (lr & 7)) << 4));
        c[nt] = __builtin_amdgcn_mfma_f32_16x16x32_bf16(ap, bv, c[nt], 0, 0, 0);
      }
    }
    DS_FENCE();   // P reads drained before next chunk's P writes (WAR)
    if (ch < 7) __syncthreads();   // next staged buffer ready for all waves
  }

  float inv[4];
#pragma unroll
  for (int off = 1; off < 16; off <<= 1)
#pragma unroll
    for (int rr = 0; rr < 4; ++rr) sum[rr] += __shfl_xor(sum[rr], off, 64);
#pragma unroll
  for (int rr = 0; rr < 4; ++rr) inv[rr] = 1.0f / sum[rr];

#pragma unroll
  for (int nt = 0; nt < 4; ++nt) {
    int hd = nt * 16 + lr;
#pragma unroll
    for (int rr = 0; rr < 4; ++rr) {
      int qrow = qbase + g * 4 + rr;
      ctx_ws[(((size_t)b * L_ + qrow) * H_ + h) * HD_ + hd] =
          f2bf(c[nt][rr] * inv[rr]);
    }
  }
}

// --------------------------------------------------------------------------
// Output GEMM — same counted-vmcnt 3-buffer pipeline, all-bf16 tiles.
// 128x128 tile, BK=32, G=4 loads/wave/step. LDS 48KB -> 3 blocks/CU.
// --------------------------------------------------------------------------
__global__ __launch_bounds__(256, 3) void gemm_out(
    const short* __restrict__ ctx, const short* __restrict__ wt3,
    const float* __restrict__ bO, float* __restrict__ out) {
  __shared__ __align__(16) char lds[49152];  // A 3x8KB | B 3x8KB
  int wgid = blockIdx.x + 4 * blockIdx.y;
  int rr_ = wgid >> 3;
  int m0 = ((wgid & 7) * 16 + (rr_ >> 2)) * 128;
  int n0 = (rr_ & 3) * 128;
  int tid = threadIdx.x, lane = tid & 63, w = tid >> 6;
  int wr = w >> 1, wc = w & 1, g = lane >> 4, lr = lane & 15;
  int cb = (lane & 3) ^ ((lane >> 2) & 3);   // 16 rows x 64B per 1KB issue

  auto stageA = [&](int ks, int bi) {
    char* Ab = lds + bi * 8192;
#pragma unroll
    for (int j = 0; j < 2; ++j) {
      int e = w * 2 + j, row = e * 16 + (lane >> 2);
      gll16(ctx + (size_t)(m0 + row) * D_ + ks * 32 + cb * 8, Ab + e * 1024);
    }
  };
  auto stageB = [&](int ks, int bi) {
    char* Bb = lds + 24576 + bi * 8192;
#pragma unroll
    for (int j = 0; j < 2; ++j) {
      int e = w * 2 + j, row = e * 16 + (lane >> 2);
      gll16(wt3 + (size_t)(n0 + row) * D_ + ks * 32 + cb * 8, Bb + e * 1024);
    }
  };

  stageA(0, 0); stageB(0, 0);
  stageA(1, 1); stageB(1, 1);
  VMCNT4;
  __builtin_amdgcn_s_barrier();
  SCHEDB;

  f32x4 acc[4][4] = {};
#pragma unroll
  for (int t = 0; t < 16; ++t) {
    if (t < 14) {
      stageA(t + 2, (t + 2) % 3);
      stageB(t + 2, (t + 2) % 3);
      SCHEDB;
    }
    const char* Ab = lds + (t % 3) * 8192;
    const char* Bb = lds + 24576 + (t % 3) * 8192;
    bf16x8 af[4], bf_[4];
#pragma unroll
    for (int i = 0; i < 4; ++i) {
      int row = wr * 64 + i * 16 + lr;             // row & 3 == lr & 3
      af[i] = *(const bf16x8*)(Ab + row * 64 + ((g ^ (lr & 3)) << 4));
    }
#pragma unroll
    for (int i = 0; i < 4; ++i) {
      int row = wc * 64 + i * 16 + lr;
      bf_[i] = *(const bf16x8*)(Bb + row * 64 + ((g ^ (lr & 3)) << 4));
    }
    __builtin_amdgcn_s_setprio(1);
#pragma unroll
    for (int mi = 0; mi < 4; ++mi)
#pragma unroll
      for (int nj = 0; nj < 4; ++nj)
        acc[mi][nj] = __builtin_amdgcn_mfma_f32_16x16x32_bf16(
            af[mi], bf_[nj], acc[mi][nj], 0, 0, 0);
    __builtin_amdgcn_s_setprio(0);
    if (t < 15) {
      if (t < 14) { VMCNT4; }
      else       { VMCNT0; }
      __builtin_amdgcn_s_barrier();
      SCHEDB;
    }
  }
#pragma unroll
  for (int mi = 0; mi < 4; ++mi) {
#pragma unroll
    for (int nj = 0; nj < 4; ++nj) {
      int n = n0 + wc * 64 + nj * 16 + lr;
      float bb = bO[n];
#pragma unroll
      for (int rr = 0; rr < 4; ++rr) {
        int m = m0 + wr * 64 + mi * 16 + g * 4 + rr;
        out[(size_t)m * D_ + n] = acc[mi][nj][rr] + bb;
      }
    }
  }
}

// --------------------------------------------------------------------------
extern "C" void kernel_launch(void* const* d_in, const int* in_sizes, int n_in,
                              void* d_out, int out_size, void* d_ws,
                              size_t ws_size, hipStream_t stream) {
  const float* query = (const float*)d_in[0];
  const float* key   = (const float*)d_in[1];
  const float* value = (const float*)d_in[2];
  const float* mask  = (const float*)d_in[3];
  // d_in[4..8]: edge/path inputs — bias is constant along the softmax axis,
  // so it cancels exactly; unused.
  const float* WQ = (const float*)d_in[9];
  const float* bQ = (const float*)d_in[10];
  const float* WK = (const float*)d_in[11];
  const float* bK = (const float*)d_in[12];
  const float* WV = (const float*)d_in[13];
  const float* bV = (const float*)d_in[14];
  const float* WO = (const float*)d_in[15];
  const float* bO = (const float*)d_in[16];

  short* ws  = (short*)d_ws;
  short* wt  = ws;
  short* q   = ws + 1048576;
  short* k   = q + 8388608;
  short* vt  = k + 8388608;
  short* ctx = vt + 8388608;   // total 34,603,008 shorts = 69.2 MB
  float* out = (float*)d_out;

  wt_kernel<<<dim3(16, 16, 4), 256, 0, stream>>>(WQ, WK, WV, WO, wt);
  gemm_qkv<<<dim3(4, 128, 3), 256, 0, stream>>>(query, key, value, wt,
                                                bQ, bK, bV, q, k, vt);
  attn_kernel<<<2048, 256, 0, stream>>>(q, k, vt, mask, ctx);
  gemm_out<<<dim3(4, 128), 256, 0, stream>>>(ctx, wt + 3 * 262144, bO, out);
}